// Round 15
// baseline (1032.392 us; speedup 1.0000x reference)
//
#include <hip/hip_runtime.h>

namespace {

constexpr int BATCH = 8;
constexpr int CH    = 256;   // C
constexpr int HW    = 2304;  // 48*48
constexpr int IMG   = 48;
constexpr int CG    = 64;

typedef __bf16 bf16x8 __attribute__((ext_vector_type(8)));
typedef __bf16 bf16x4 __attribute__((ext_vector_type(4)));
typedef float  f32x4  __attribute__((ext_vector_type(4)));
typedef unsigned u32x4 __attribute__((ext_vector_type(4)));

constexpr int ROWB = 40;     // proj LDS row stride
constexpr int CSTR = 40;     // conv LDS stride

// ---- ws layout (bytes) ----
constexpr size_t BF_SLAB = (size_t)BATCH * HW * CH * 2;      // 9,437,184
constexpr size_t QT1_OFF = 0;
constexpr size_t KT1_OFF = 1 * BF_SLAB;
constexpr size_t VB1_OFF = 2 * BF_SLAB;                      // bf16 [B][256][HW]
constexpr size_t QT2_OFF = 3 * BF_SLAB;
constexpr size_t KT2_OFF = 4 * BF_SLAB;
constexpr size_t VB2_OFF = 5 * BF_SLAB;
constexpr size_t AT_OFF  = 6 * BF_SLAB;                      // bf16 [B][HW][512]
constexpr size_t A1_OFF  = AT_OFF + (size_t)BATCH * HW * 512 * 2;
constexpr size_t A2_OFF  = A1_OFF + (size_t)BATCH * CH * HW * 4;
constexpr size_t HB_OFF  = A2_OFF + (size_t)BATCH * CH * HW * 4;
constexpr size_t G0_OFF  = HB_OFF + (size_t)BATCH * CG * HW * 4;
constexpr size_t WT_OFF  = G0_OFF + (size_t)BATCH * HW * 4;
// end ~= 112 MB; P4 (conv partials) aliases QT1/KT1 slabs.

// pack two floats to one dword of 2 bf16 (compiler picks the cvt ops; m240)
__device__ __forceinline__ unsigned pk2(float lo, float hi) {
    unsigned short a = __builtin_bit_cast(unsigned short, (__bf16)lo);
    unsigned short b = __builtin_bit_cast(unsigned short, (__bf16)hi);
    return (unsigned)a | ((unsigned)b << 16);
}

// stage 16 fp32 elems/thread (convert to bf16) into [128][ROWB] LDS (256-thr)
__device__ __forceinline__ void stage_f32(const float* __restrict__ src, size_t srcStride,
                                          __bf16* dst, int t) {
    const int r = t & 127, s = t >> 7;
    const float4* sp = reinterpret_cast<const float4*>(src + (size_t)r * srcStride + s * 16);
    float4 f0 = sp[0], f1 = sp[1], f2 = sp[2], f3 = sp[3];
    bf16x8 v0, v1;
    v0[0]=(__bf16)f0.x; v0[1]=(__bf16)f0.y; v0[2]=(__bf16)f0.z; v0[3]=(__bf16)f0.w;
    v0[4]=(__bf16)f1.x; v0[5]=(__bf16)f1.y; v0[6]=(__bf16)f1.z; v0[7]=(__bf16)f1.w;
    v1[0]=(__bf16)f2.x; v1[1]=(__bf16)f2.y; v1[2]=(__bf16)f2.z; v1[3]=(__bf16)f2.w;
    v1[4]=(__bf16)f3.x; v1[5]=(__bf16)f3.y; v1[6]=(__bf16)f3.z; v1[7]=(__bf16)f3.w;
    bf16x8* dp = reinterpret_cast<bf16x8*>(dst + r * ROWB + s * 16);
    dp[0] = v0;
    dp[1] = v1;
}

// 4-wave 128x128 MFMA step (proj) [proven r3]
__device__ __forceinline__ void frag_step(const __bf16* As, const __bf16* Bs,
                                          f32x4 (&acc)[4][4], int lane, int wm, int wn) {
    const int r = lane & 15, g = lane >> 4;
    bf16x8 a[4], b[4];
#pragma unroll
    for (int i = 0; i < 4; ++i) {
        a[i] = *reinterpret_cast<const bf16x8*>(As + (wm * 64 + i * 16 + r) * ROWB + g * 8);
        b[i] = *reinterpret_cast<const bf16x8*>(Bs + (wn * 64 + i * 16 + r) * ROWB + g * 8);
    }
#pragma unroll
    for (int i = 0; i < 4; ++i)
#pragma unroll
        for (int j = 0; j < 4; ++j)
            acc[i][j] = __builtin_amdgcn_mfma_f32_16x16x32_bf16(a[i], b[j], acc[i][j], 0, 0, 0);
}

// ---------------------------------------------------------------------------
// proj3: Q/K TRANSPOSED bf16 [B][HW][256]; V natural [B][256][HW]. [proven r3-r14]
__global__ __launch_bounds__(256) void proj3_mfma(
    const float* __restrict__ Xsrc, const float* __restrict__ Xg,
    const float* __restrict__ wq, const float* __restrict__ wk,
    const float* __restrict__ wv, const float* __restrict__ bv,
    __bf16* __restrict__ QT, __bf16* __restrict__ KT, __bf16* __restrict__ VB)
{
    __shared__ __bf16 As[128 * ROWB];
    __shared__ __bf16 Bs[128 * ROWB];
    const int p = blockIdx.z >> 3;      // 0=Q 1=K 2=V
    const int b = blockIdx.z & 7;
    const float* W = (p == 0) ? wq : (p == 1) ? wk : wv;
    const float* X = (p == 0) ? Xsrc : Xg;
    const float* Xb = X + (size_t)b * CH * HW;

    const int t = threadIdx.x;
    const int lane = t & 63, wid = t >> 6;
    const int wm = wid >> 1, wn = wid & 1;
    const int m0 = blockIdx.y * 128, n0 = blockIdx.x * 128;

    f32x4 acc[4][4] = {};
    const int nB = t & 127, halfB = t >> 7;

    for (int k0 = 0; k0 < CH; k0 += 32) {
        stage_f32(W + (size_t)m0 * CH + k0, CH, As, t);
        float v[16];
#pragma unroll
        for (int kk = 0; kk < 16; ++kk)
            v[kk] = Xb[(size_t)(k0 + halfB * 16 + kk) * HW + n0 + nB];
        bf16x8 p0, p1;
#pragma unroll
        for (int kk = 0; kk < 8; ++kk) { p0[kk] = (__bf16)v[kk]; p1[kk] = (__bf16)v[kk + 8]; }
        bf16x8* dp = reinterpret_cast<bf16x8*>(Bs + nB * ROWB + halfB * 16);
        dp[0] = p0; dp[1] = p1;
        __syncthreads();
        frag_step(As, Bs, acc, lane, wm, wn);
        __syncthreads();
    }

    const int g = lane >> 4, r = lane & 15;
    if (p < 2) {
        __bf16* T = (p == 0) ? QT : KT;
#pragma unroll
        for (int mi = 0; mi < 4; ++mi)
#pragma unroll
            for (int nj = 0; nj < 4; ++nj) {
                const int mb = m0 + wm * 64 + mi * 16 + g * 4;
                const int n  = n0 + wn * 64 + nj * 16 + r;
                bf16x4 pk;
#pragma unroll
                for (int q = 0; q < 4; ++q) pk[q] = (__bf16)acc[mi][nj][q];
                *reinterpret_cast<bf16x4*>(T + ((size_t)b * HW + n) * CH + mb) = pk;
            }
    } else {
#pragma unroll
        for (int mi = 0; mi < 4; ++mi)
#pragma unroll
            for (int nj = 0; nj < 4; ++nj) {
                const int mb = m0 + wm * 64 + mi * 16 + g * 4;
                const int n  = n0 + wn * 64 + nj * 16 + r;
#pragma unroll
                for (int q = 0; q < 4; ++q)
                    VB[((size_t)b * CH + mb + q) * HW + n] = (__bf16)(acc[mi][nj][q] + bv[mb + q]);
            }
    }
}

// ---------------------------------------------------------------------------
// fused_flash v9: ZERO-BARRIER wave-independent flash. Each wave owns 16
// q-rows end-to-end: S (swapped, K direct from global), in-lane softmax,
// P kept in REGISTERS and redistributed to A-fragments via wave-local shfl,
// PV = mfma(P, V) with V direct from global. No LDS, no __syncthreads.
// 256 thr (4 indep waves), QBLK=64. grid 576, XCD-swizzled.
__global__ __launch_bounds__(256, 2) void fused_flash(
    const __bf16* __restrict__ QT1, const __bf16* __restrict__ KT1, const __bf16* __restrict__ VB1,
    const __bf16* __restrict__ QT2, const __bf16* __restrict__ KT2, const __bf16* __restrict__ VB2,
    const float* __restrict__ x1, const float* __restrict__ x2,
    const float* __restrict__ g1, const float* __restrict__ g2,
    float* __restrict__ A1, float* __restrict__ A2, __bf16* __restrict__ AT)
{
    // XCD swizzle: 576 = 8 * 72; contiguous 72-block chunk (2 z) per XCD
    const int bid  = blockIdx.x;
    const int work = (bid & 7) * 72 + (bid >> 3);
    const int z = work / 36, ntile = work - z * 36;

    const int att = z >> 3, b = z & 7;
    const __bf16* QT = att ? QT2 : QT1;
    const __bf16* KT = att ? KT2 : KT1;
    const __bf16* VB = att ? VB2 : VB1;
    const float* src = att ? x2 : x1;
    const float* gmp = att ? g2 : g1;
    float* A         = att ? A2 : A1;
    const int aoff   = att ? CH : 0;

    const int t = threadIdx.x, lane = t & 63, w = t >> 6;
    const int r = lane & 15, g = lane >> 4;
    const int n0 = ntile * 64;
    const __bf16* KTb = KT + (size_t)b * HW * CH;
    const __bf16* VBb = VB + (size_t)b * CH * HW;

    // shuffle geometry for P-redistribution (derived; see round-15 notes):
    // target lane (r,g) elem e of pa[ks] comes from src lane r + 16*(2(g&1)+(e>=4)),
    // dword dwj[2ks + (g>>1)][(e%4)>>1? packed q-pairs]
    const int sb  = r + (((lane >> 4) & 1) << 5);   // src for e<4  (and +16 for e>=4)
    const bool ghi = ((lane >> 5) & 1);             // g>>1: selects dwj[2ks+1]

    // Q rows in registers: q-row n0 + w*16 + r, full K=256
    bf16x8 qf[8];
    {
        const __bf16* qrow = QT + ((size_t)b * HW + n0 + w * 16 + r) * CH;
#pragma unroll
        for (int kc = 0; kc < 8; ++kc)
            qf[kc] = *reinterpret_cast<const bf16x8*>(qrow + kc * 32 + g * 8);
    }

    float m_run = -3.0e38f;
    float s_run = 0.f;
    f32x4 accO2[16] = {};   // accO2[cb][q]: O[n = g*4+q][c = cb*16 + r]

    for (int tile = 0; tile < 18; ++tile) {
        const int m0 = tile * 128;
        // ---- S: accS[j][q] = S[q-row r][m = j*16 + g*4 + q], K from global
        f32x4 accS[8] = {};
#pragma unroll
        for (int kk = 0; kk < 8; ++kk) {
            const bf16x8 qv = qf[kk];
#pragma unroll
            for (int j = 0; j < 8; ++j) {
                const bf16x8 kf = *reinterpret_cast<const bf16x8*>(
                    KTb + (size_t)(m0 + j * 16 + r) * CH + kk * 32 + g * 8);
                accS[j] = __builtin_amdgcn_mfma_f32_16x16x32_bf16(kf, qv, accS[j], 0, 0, 0);
            }
        }
        // ---- in-lane online softmax + bf16 pack (P stays in registers)
        unsigned dwj[8][2];
        float scale;
        {
            float mj[8];
#pragma unroll
            for (int j = 0; j < 8; ++j)
                mj[j] = fmaxf(fmaxf(accS[j][0], accS[j][1]), fmaxf(accS[j][2], accS[j][3]));
            float m03 = fmaxf(fmaxf(mj[0], mj[1]), fmaxf(mj[2], mj[3]));
            float m47 = fmaxf(fmaxf(mj[4], mj[5]), fmaxf(mj[6], mj[7]));
            float tmax = fmaxf(m03, m47);
            tmax = fmaxf(tmax, __shfl_xor(tmax, 16));
            tmax = fmaxf(tmax, __shfl_xor(tmax, 32));
            const float nm = fmaxf(m_run, tmax);
            float tsj[8];
#pragma unroll
            for (int j = 0; j < 8; ++j) {
                const float pe0 = __expf(accS[j][0] - nm);
                const float pe1 = __expf(accS[j][1] - nm);
                const float pe2 = __expf(accS[j][2] - nm);
                const float pe3 = __expf(accS[j][3] - nm);
                tsj[j] = (pe0 + pe1) + (pe2 + pe3);
                dwj[j][0] = pk2(pe0, pe1);
                dwj[j][1] = pk2(pe2, pe3);
            }
            float ts = ((tsj[0] + tsj[1]) + (tsj[2] + tsj[3])) +
                       ((tsj[4] + tsj[5]) + (tsj[6] + tsj[7]));
            ts += __shfl_xor(ts, 16);
            ts += __shfl_xor(ts, 32);
            scale = __expf(m_run - nm);
            s_run = s_run * scale + ts;
            m_run = nm;
        }
        // ---- rescale accO2 by per-output-row scale (wave-local shfl)
        {
            float sc4[4];
#pragma unroll
            for (int q = 0; q < 4; ++q) sc4[q] = __shfl(scale, g * 4 + q);
#pragma unroll
            for (int cb = 0; cb < 16; ++cb)
#pragma unroll
                for (int q = 0; q < 4; ++q) accO2[cb][q] *= sc4[q];
        }
        // ---- redistribute P to A-operand fragments (wave-local shfl)
        bf16x8 pa[4];
#pragma unroll
        for (int ks = 0; ks < 4; ++ks) {
            const unsigned a0 = (unsigned)__shfl((int)dwj[2 * ks][0], sb);
            const unsigned b0 = (unsigned)__shfl((int)dwj[2 * ks + 1][0], sb);
            const unsigned a1 = (unsigned)__shfl((int)dwj[2 * ks][1], sb);
            const unsigned b1 = (unsigned)__shfl((int)dwj[2 * ks + 1][1], sb);
            const unsigned a2 = (unsigned)__shfl((int)dwj[2 * ks][0], sb + 16);
            const unsigned b2 = (unsigned)__shfl((int)dwj[2 * ks + 1][0], sb + 16);
            const unsigned a3 = (unsigned)__shfl((int)dwj[2 * ks][1], sb + 16);
            const unsigned b3 = (unsigned)__shfl((int)dwj[2 * ks + 1][1], sb + 16);
            u32x4 dd;
            dd.x = ghi ? b0 : a0;
            dd.y = ghi ? b1 : a1;
            dd.z = ghi ? b2 : a2;
            dd.w = ghi ? b3 : a3;
            pa[ks] = __builtin_bit_cast(bf16x8, dd);
        }
        // ---- PV: O[n][c] += P[n][m] V[c][m]; V direct from global
        __builtin_amdgcn_s_setprio(1);
#pragma unroll
        for (int cb = 0; cb < 16; ++cb) {
#pragma unroll
            for (int ks = 0; ks < 4; ++ks) {
                const bf16x8 vf = *reinterpret_cast<const bf16x8*>(
                    VBb + (size_t)(cb * 16 + r) * HW + m0 + ks * 32 + g * 8);
                accO2[cb] = __builtin_amdgcn_mfma_f32_16x16x32_bf16(pa[ks], vf, accO2[cb], 0, 0, 0);
            }
        }
        __builtin_amdgcn_s_setprio(0);
    }

    // ---- epilogue: out = gamma * (1/s) * O + src   (O[n=g*4+q][c=cb*16+r])
    const float inv = 1.f / s_run;
    float is4[4];
#pragma unroll
    for (int q = 0; q < 4; ++q) is4[q] = __shfl(inv, g * 4 + q);
    const float gm = gmp[0];
#pragma unroll
    for (int cb = 0; cb < 16; ++cb) {
        const int c = cb * 16 + r;
#pragma unroll
        for (int q = 0; q < 4; ++q) {
            const int n = n0 + w * 16 + g * 4 + q;
            const size_t idx = ((size_t)b * CH + c) * HW + n;
            const float val = gm * is4[q] * accO2[cb][q] + src[idx];
            A[idx] = val;
            AT[((size_t)b * HW + n) * 512 + aoff + c] = (__bf16)val;
        }
    }
}

// ---------------------------------------------------------------------------
// wprep: fw1 [64][512*9] fp32 -> WT bf16 [tap][m][512]
__global__ __launch_bounds__(256) void wprep(const float* __restrict__ fw1,
                                             __bf16* __restrict__ WT)
{
    const int i = blockIdx.x * 256 + threadIdx.x;   // 9*64*512 exact
    const int tap = i >> 15;
    const int rem = i & 32767;
    const int m = rem >> 9, c = rem & 511;
    WT[i] = (__bf16)fw1[(size_t)m * 4608 + c * 9 + tap];
}

// ---------------------------------------------------------------------------
// conv1 v2 [proven r4-r14 verbatim]
__global__ __launch_bounds__(256) void conv1_v2(
    const __bf16* __restrict__ AT, const __bf16* __restrict__ WT,
    float* __restrict__ P4)
{
    __shared__ __bf16 A9[9 * 64 * CSTR];
    __shared__ __bf16 HALO[240 * CSTR];
    const int kc = blockIdx.y, b = blockIdx.z, n0 = blockIdx.x * 128;
    const int t = threadIdx.x, lane = t & 63, wid = t >> 6;
    const int r = lane & 15, g = lane >> 4;

    int yj[2], xj[2];
#pragma unroll
    for (int j = 0; j < 2; ++j) {
        const int p = n0 + wid * 32 + j * 16 + r;
        yj[j] = p / IMG; xj[j] = p - yj[j] * IMG;
    }

    f32x4 acc[4][2] = {};

#pragma unroll 1
    for (int st = 0; st < 4; ++st) {
        const int cbase = kc * 128 + st * 32;
        if (t < 240) {
            const int nn = n0 - 56 + t;
            bf16x8 h0 = {}, h1 = {}, h2 = {}, h3 = {};
            if (nn >= 0 && nn < HW) {
                const bf16x8* sp = reinterpret_cast<const bf16x8*>(
                    AT + ((size_t)b * HW + nn) * 512 + cbase);
                h0 = sp[0]; h1 = sp[1]; h2 = sp[2]; h3 = sp[3];
            }
            bf16x8* dp = reinterpret_cast<bf16x8*>(HALO + t * CSTR);
            dp[0] = h0; dp[1] = h1; dp[2] = h2; dp[3] = h3;
        }
        {
            const int m = t >> 2, seg = t & 3;
#pragma unroll
            for (int tap = 0; tap < 9; ++tap)
                *reinterpret_cast<bf16x8*>(A9 + (tap * 64 + m) * CSTR + seg * 8) =
                    *reinterpret_cast<const bf16x8*>(WT + ((size_t)tap * 64 + m) * 512 + cbase + seg * 8);
        }
        __syncthreads();
#pragma unroll 1
        for (int tap = 0; tap < 9; ++tap) {
            const int dy = tap / 3 - 1;
            const int dx = tap - (tap / 3) * 3 - 1;
            bf16x8 bb[2];
#pragma unroll
            for (int j = 0; j < 2; ++j) {
                const bool valid = ((unsigned)(yj[j] + dy) < (unsigned)IMG) &&
                                   ((unsigned)(xj[j] + dx) < (unsigned)IMG);
                const int row = wid * 32 + j * 16 + r + 56 + dy * IMG + dx;
                bf16x8 v = {};
                if (valid) v = *reinterpret_cast<const bf16x8*>(HALO + row * CSTR + g * 8);
                bb[j] = v;
            }
            bf16x8 a[4];
#pragma unroll
            for (int i = 0; i < 4; ++i)
                a[i] = *reinterpret_cast<const bf16x8*>(A9 + (tap * 64 + i * 16 + r) * CSTR + g * 8);
#pragma unroll
            for (int i = 0; i < 4; ++i)
#pragma unroll
                for (int j = 0; j < 2; ++j)
                    acc[i][j] = __builtin_amdgcn_mfma_f32_16x16x32_bf16(a[i], bb[j], acc[i][j], 0, 0, 0);
        }
        __syncthreads();
    }
#pragma unroll
    for (int mi = 0; mi < 4; ++mi)
#pragma unroll
        for (int nj = 0; nj < 2; ++nj) {
            const int m = mi * 16 + g * 4;
            const int n = n0 + wid * 32 + nj * 16 + r;
#pragma unroll
            for (int q = 0; q < 4; ++q)
                P4[(((size_t)kc * BATCH + b) * CG + m + q) * HW + n] = acc[mi][nj][q];
        }
}

// ---------------------------------------------------------------------------
__global__ __launch_bounds__(256) void reduce_hb(
    const float* __restrict__ P4, const float* __restrict__ fb1,
    float* __restrict__ HB)
{
    const int idx = blockIdx.x * 256 + threadIdx.x;
    constexpr size_t STRIDE = (size_t)BATCH * CG * HW;
    const int m = (idx / HW) & 63;
    float s = P4[idx] + P4[idx + STRIDE] + P4[idx + 2 * STRIDE] + P4[idx + 3 * STRIDE];
    HB[idx] = fmaxf(s + fb1[m], 0.f);
}

// ---------------------------------------------------------------------------
__global__ __launch_bounds__(256) void gates_v2(
    const float* __restrict__ hbuf, const float* __restrict__ fw2,
    const float* __restrict__ fb2, float* __restrict__ g0buf)
{
    __shared__ float w2s[1152];
    __shared__ float par[2][4][64];
    const int t = threadIdx.x;
    for (int i = t; i < 1152; i += 256) w2s[i] = fw2[i];
    __syncthreads();
    const int px = t & 63, grp = t >> 6;
    const int idx = blockIdx.x * 64 + px;
    const int b = idx / HW;
    const int n = idx - b * HW;
    const int y = n / IMG, x = n - (n / IMG) * IMG;
    float c0 = 0.f, c1 = 0.f;
    const float* hb = hbuf + ((size_t)b * CG + grp * 16) * HW;
    for (int ci = 0; ci < 16; ++ci) {
        const float* hp = hb + (size_t)ci * HW;
        const float* w0 = &w2s[(grp * 16 + ci) * 9];
        const float* w1 = &w2s[576 + (grp * 16 + ci) * 9];
#pragma unroll
        for (int tap = 0; tap < 9; ++tap) {
            const int dy = tap / 3 - 1, dx = tap % 3 - 1;
            const int yy = y + dy, xx = x + dx;
            if (yy >= 0 && yy < IMG && xx >= 0 && xx < IMG) {
                const float hv = hp[yy * IMG + xx];
                c0 = fmaf(hv, w0[tap], c0);
                c1 = fmaf(hv, w1[tap], c1);
            }
        }
    }
    par[0][grp][px] = c0;
    par[1][grp][px] = c1;
    __syncthreads();
    if (t < 64) {
        const float s0 = par[0][0][t] + par[0][1][t] + par[0][2][t] + par[0][3][t] + fb2[0];
        const float s1 = par[1][0][t] + par[1][1][t] + par[1][2][t] + par[1][3][t] + fb2[1];
        g0buf[blockIdx.x * 64 + t] = 1.f / (1.f + __expf(s1 - s0));
    }
}

// ---------------------------------------------------------------------------
__global__ __launch_bounds__(256) void blend_kernel(
    const float* __restrict__ att1, const float* __restrict__ att2,
    const float* __restrict__ g0buf, float* __restrict__ out)
{
    const int i = blockIdx.x * 256 + threadIdx.x;
    const int r = i / 576;
    const int q = i - r * 576;
    const int b = r >> 8;
    const float4 a1 = reinterpret_cast<const float4*>(att1)[i];
    const float4 a2 = reinterpret_cast<const float4*>(att2)[i];
    const float4 g  = *reinterpret_cast<const float4*>(&g0buf[(size_t)b * HW + q * 4]);
    float4 o;
    o.x = g.x * a1.x + (1.f - g.x) * a2.x;
    o.y = g.y * a1.y + (1.f - g.y) * a2.y;
    o.z = g.z * a1.z + (1.f - g.z) * a2.z;
    o.w = g.w * a1.w + (1.f - g.w) * a2.w;
    reinterpret_cast<float4*>(out)[i] = o;
}

} // namespace

extern "C" void kernel_launch(void* const* d_in, const int* in_sizes, int n_in,
                              void* d_out, int out_size, void* d_ws, size_t ws_size,
                              hipStream_t stream)
{
    const float* x1  = (const float*)d_in[0];
    const float* x2  = (const float*)d_in[1];
    const float* wq1 = (const float*)d_in[2];
    const float* wk1 = (const float*)d_in[3];
    const float* wv1 = (const float*)d_in[4];
    const float* bv1 = (const float*)d_in[5];
    const float* g1  = (const float*)d_in[6];
    const float* wq2 = (const float*)d_in[7];
    const float* wk2 = (const float*)d_in[8];
    const float* wv2 = (const float*)d_in[9];
    const float* bv2 = (const float*)d_in[10];
    const float* g2  = (const float*)d_in[11];
    const float* fw1 = (const float*)d_in[12];
    const float* fb1 = (const float*)d_in[13];
    const float* fw2 = (const float*)d_in[14];
    const float* fb2 = (const float*)d_in[15];
    float* out = (float*)d_out;
    char*  wsb = (char*)d_ws;

    __bf16* QT1 = (__bf16*)(wsb + QT1_OFF);
    __bf16* KT1 = (__bf16*)(wsb + KT1_OFF);
    __bf16* VB1 = (__bf16*)(wsb + VB1_OFF);
    __bf16* QT2 = (__bf16*)(wsb + QT2_OFF);
    __bf16* KT2 = (__bf16*)(wsb + KT2_OFF);
    __bf16* VB2 = (__bf16*)(wsb + VB2_OFF);
    __bf16* AT  = (__bf16*)(wsb + AT_OFF);
    float*  A1  = (float*)(wsb + A1_OFF);
    float*  A2  = (float*)(wsb + A2_OFF);
    float*  HB  = (float*)(wsb + HB_OFF);
    float*  G0  = (float*)(wsb + G0_OFF);
    __bf16* WT  = (__bf16*)(wsb + WT_OFF);
    float*  P4  = (float*)(wsb + QT1_OFF);   // alias: free after attention

    (void)in_sizes; (void)n_in; (void)out_size; (void)ws_size;

    proj3_mfma<<<dim3(18, 2, 24), 256, 0, stream>>>(x1, x2, wq1, wk1, wv1, bv1, QT1, KT1, VB1);
    proj3_mfma<<<dim3(18, 2, 24), 256, 0, stream>>>(x2, x1, wq2, wk2, wv2, bv2, QT2, KT2, VB2);
    wprep<<<dim3(1152), 256, 0, stream>>>(fw1, WT);

    fused_flash<<<dim3(576), 256, 0, stream>>>(
        QT1, KT1, VB1, QT2, KT2, VB2, x1, x2, g1, g2, A1, A2, AT);

    conv1_v2<<<dim3(18, 4, 8), 256, 0, stream>>>(AT, WT, P4);
    reduce_hb<<<dim3(4608), 256, 0, stream>>>(P4, fb1, HB);
    gates_v2<<<dim3(288), 256, 0, stream>>>(HB, fw2, fb2, G0);
    blend_kernel<<<dim3(4608), 256, 0, stream>>>(A1, A2, G0, out);
}

// Round 16
// 674.203 us; speedup vs baseline: 1.5313x; 1.5313x over previous
//
#include <hip/hip_runtime.h>

namespace {

constexpr int BATCH = 8;
constexpr int CH    = 256;   // C
constexpr int HW    = 2304;  // 48*48
constexpr int IMG   = 48;
constexpr int CG    = 64;

typedef __bf16 bf16x8 __attribute__((ext_vector_type(8)));
typedef __bf16 bf16x4 __attribute__((ext_vector_type(4)));
typedef float  f32x4  __attribute__((ext_vector_type(4)));
typedef unsigned u32x4 __attribute__((ext_vector_type(4)));

constexpr int ROWB = 40;     // proj LDS row stride
constexpr int CSTR = 40;     // conv LDS stride
constexpr int KQ_ELE = 8192; // one K quarter: 128 rows x 64 cols bf16 (16 KB), LINEAR

// ---- ws layout (bytes) ----
constexpr size_t BF_SLAB = (size_t)BATCH * HW * CH * 2;      // 9,437,184
constexpr size_t QT1_OFF = 0;
constexpr size_t KT1_OFF = 1 * BF_SLAB;
constexpr size_t VB1_OFF = 2 * BF_SLAB;                      // bf16 [B][256][HW]
constexpr size_t QT2_OFF = 3 * BF_SLAB;
constexpr size_t KT2_OFF = 4 * BF_SLAB;
constexpr size_t VB2_OFF = 5 * BF_SLAB;
constexpr size_t AT_OFF  = 6 * BF_SLAB;                      // bf16 [B][HW][512]
constexpr size_t A1_OFF  = AT_OFF + (size_t)BATCH * HW * 512 * 2;
constexpr size_t A2_OFF  = A1_OFF + (size_t)BATCH * CH * HW * 4;
constexpr size_t HB_OFF  = A2_OFF + (size_t)BATCH * CH * HW * 4;
constexpr size_t G0_OFF  = HB_OFF + (size_t)BATCH * CG * HW * 4;
constexpr size_t WT_OFF  = G0_OFF + (size_t)BATCH * HW * 4;
// end ~= 112 MB; P4 (conv partials, now 2 chunks = 37.7 MB) aliases QT1 slabs.

// async global->LDS DMA, 16B per lane (issued where written; not sinkable)
__device__ __forceinline__ void dma16(const __bf16* g, __bf16* l) {
    __builtin_amdgcn_global_load_lds(
        (const __attribute__((address_space(1))) void*)g,
        (__attribute__((address_space(3))) void*)l,
        16, 0, 0);
}

// issue one K quarter (128 rows x 64 cols) into a linear LDS slot with
// pre-swizzled SOURCE granule (rule #21; proven r13/r14)
__device__ __forceinline__ void issue_k_dma(const __bf16* __restrict__ KTb,
                                            __bf16* Kslot, int m0_i, int qq,
                                            int w, int lane) {
    const int lrow = lane >> 3;               // 0..7
    const int lg   = (lane & 7) ^ lrow;       // swizzled source granule
    const int colb = qq * 64 + lg * 8;
#pragma unroll
    for (int qi = 0; qi < 4; ++qi) {
        const int row = (w * 4 + qi) * 8 + lrow;
        dma16(KTb + (size_t)(m0_i + row) * CH + colb,
              Kslot + (w * 4 + qi) * 512);
    }
}

// pack two floats to one dword of 2 bf16 [proven r15]
__device__ __forceinline__ unsigned pk2(float lo, float hi) {
    unsigned short a = __builtin_bit_cast(unsigned short, (__bf16)lo);
    unsigned short b = __builtin_bit_cast(unsigned short, (__bf16)hi);
    return (unsigned)a | ((unsigned)b << 16);
}

// stage 16 fp32 elems/thread (convert to bf16) into [128][ROWB] LDS (256-thr)
__device__ __forceinline__ void stage_f32(const float* __restrict__ src, size_t srcStride,
                                          __bf16* dst, int t) {
    const int r = t & 127, s = t >> 7;
    const float4* sp = reinterpret_cast<const float4*>(src + (size_t)r * srcStride + s * 16);
    float4 f0 = sp[0], f1 = sp[1], f2 = sp[2], f3 = sp[3];
    bf16x8 v0, v1;
    v0[0]=(__bf16)f0.x; v0[1]=(__bf16)f0.y; v0[2]=(__bf16)f0.z; v0[3]=(__bf16)f0.w;
    v0[4]=(__bf16)f1.x; v0[5]=(__bf16)f1.y; v0[6]=(__bf16)f1.z; v0[7]=(__bf16)f1.w;
    v1[0]=(__bf16)f2.x; v1[1]=(__bf16)f2.y; v1[2]=(__bf16)f2.z; v1[3]=(__bf16)f2.w;
    v1[4]=(__bf16)f3.x; v1[5]=(__bf16)f3.y; v1[6]=(__bf16)f3.z; v1[7]=(__bf16)f3.w;
    bf16x8* dp = reinterpret_cast<bf16x8*>(dst + r * ROWB + s * 16);
    dp[0] = v0;
    dp[1] = v1;
}

// 4-wave 128x128 MFMA step (proj) [proven r3]
__device__ __forceinline__ void frag_step(const __bf16* As, const __bf16* Bs,
                                          f32x4 (&acc)[4][4], int lane, int wm, int wn) {
    const int r = lane & 15, g = lane >> 4;
    bf16x8 a[4], b[4];
#pragma unroll
    for (int i = 0; i < 4; ++i) {
        a[i] = *reinterpret_cast<const bf16x8*>(As + (wm * 64 + i * 16 + r) * ROWB + g * 8);
        b[i] = *reinterpret_cast<const bf16x8*>(Bs + (wn * 64 + i * 16 + r) * ROWB + g * 8);
    }
#pragma unroll
    for (int i = 0; i < 4; ++i)
#pragma unroll
        for (int j = 0; j < 4; ++j)
            acc[i][j] = __builtin_amdgcn_mfma_f32_16x16x32_bf16(a[i], b[j], acc[i][j], 0, 0, 0);
}

// ---------------------------------------------------------------------------
// proj3: Q/K TRANSPOSED bf16 [B][HW][256]; V natural [B][256][HW]. [proven r3-r14]
__global__ __launch_bounds__(256) void proj3_mfma(
    const float* __restrict__ Xsrc, const float* __restrict__ Xg,
    const float* __restrict__ wq, const float* __restrict__ wk,
    const float* __restrict__ wv, const float* __restrict__ bv,
    __bf16* __restrict__ QT, __bf16* __restrict__ KT, __bf16* __restrict__ VB)
{
    __shared__ __bf16 As[128 * ROWB];
    __shared__ __bf16 Bs[128 * ROWB];
    const int p = blockIdx.z >> 3;      // 0=Q 1=K 2=V
    const int b = blockIdx.z & 7;
    const float* W = (p == 0) ? wq : (p == 1) ? wk : wv;
    const float* X = (p == 0) ? Xsrc : Xg;
    const float* Xb = X + (size_t)b * CH * HW;

    const int t = threadIdx.x;
    const int lane = t & 63, wid = t >> 6;
    const int wm = wid >> 1, wn = wid & 1;
    const int m0 = blockIdx.y * 128, n0 = blockIdx.x * 128;

    f32x4 acc[4][4] = {};
    const int nB = t & 127, halfB = t >> 7;

    for (int k0 = 0; k0 < CH; k0 += 32) {
        stage_f32(W + (size_t)m0 * CH + k0, CH, As, t);
        float v[16];
#pragma unroll
        for (int kk = 0; kk < 16; ++kk)
            v[kk] = Xb[(size_t)(k0 + halfB * 16 + kk) * HW + n0 + nB];
        bf16x8 p0, p1;
#pragma unroll
        for (int kk = 0; kk < 8; ++kk) { p0[kk] = (__bf16)v[kk]; p1[kk] = (__bf16)v[kk + 8]; }
        bf16x8* dp = reinterpret_cast<bf16x8*>(Bs + nB * ROWB + halfB * 16);
        dp[0] = p0; dp[1] = p1;
        __syncthreads();
        frag_step(As, Bs, acc, lane, wm, wn);
        __syncthreads();
    }

    const int g = lane >> 4, r = lane & 15;
    if (p < 2) {
        __bf16* T = (p == 0) ? QT : KT;
#pragma unroll
        for (int mi = 0; mi < 4; ++mi)
#pragma unroll
            for (int nj = 0; nj < 4; ++nj) {
                const int mb = m0 + wm * 64 + mi * 16 + g * 4;
                const int n  = n0 + wn * 64 + nj * 16 + r;
                bf16x4 pk;
#pragma unroll
                for (int q = 0; q < 4; ++q) pk[q] = (__bf16)acc[mi][nj][q];
                *reinterpret_cast<bf16x4*>(T + ((size_t)b * HW + n) * CH + mb) = pk;
            }
    } else {
#pragma unroll
        for (int mi = 0; mi < 4; ++mi)
#pragma unroll
            for (int nj = 0; nj < 4; ++nj) {
                const int mb = m0 + wm * 64 + mi * 16 + g * 4;
                const int n  = n0 + wn * 64 + nj * 16 + r;
#pragma unroll
                for (int q = 0; q < 4; ++q)
                    VB[((size_t)b * CH + mb + q) * HW + n] = (__bf16)(acc[mi][nj][q] + bv[mb + q]);
            }
    }
}

// ---------------------------------------------------------------------------
// fused_flash v10: r14's DMA K-ring (3 slots, 2-ahead, counted vmcnt) +
// r15's REGISTER-P softmax/PV (verified correct). 4 barriers/tile, 48 KB LDS,
// no P LDS, V at-use from global. 256 thr, QBLK=64. grid 576, XCD-swizzled.
__global__ __launch_bounds__(256, 2) void fused_flash(
    const __bf16* __restrict__ QT1, const __bf16* __restrict__ KT1, const __bf16* __restrict__ VB1,
    const __bf16* __restrict__ QT2, const __bf16* __restrict__ KT2, const __bf16* __restrict__ VB2,
    const float* __restrict__ x1, const float* __restrict__ x2,
    const float* __restrict__ g1, const float* __restrict__ g2,
    float* __restrict__ A1, float* __restrict__ A2, __bf16* __restrict__ AT)
{
    __shared__ __bf16 Ks[3 * KQ_ELE];      // 48 KB, K ring only

    const int bid  = blockIdx.x;
    const int work = (bid & 7) * 72 + (bid >> 3);
    const int z = work / 36, ntile = work - z * 36;

    const int att = z >> 3, b = z & 7;
    const __bf16* QT = att ? QT2 : QT1;
    const __bf16* KT = att ? KT2 : KT1;
    const __bf16* VB = att ? VB2 : VB1;
    const float* src = att ? x2 : x1;
    const float* gmp = att ? g2 : g1;
    float* A         = att ? A2 : A1;
    const int aoff   = att ? CH : 0;

    const int t = threadIdx.x, lane = t & 63, w = t >> 6;
    const int r = lane & 15, g = lane >> 4;
    const int rs7 = r & 7;
    const int n0 = ntile * 64;
    const __bf16* KTb = KT + (size_t)b * HW * CH;
    const __bf16* VBb = VB + (size_t)b * CH * HW;

    // shuffle geometry for P-redistribution [proven r15]
    const int sb  = r + ((g & 1) << 5);
    const bool ghi = ((g >> 1) & 1);

    // Q rows in registers
    bf16x8 qf[8];
    {
        const __bf16* qrow = QT + ((size_t)b * HW + n0 + w * 16 + r) * CH;
#pragma unroll
        for (int kc = 0; kc < 8; ++kc)
            qf[kc] = *reinterpret_cast<const bf16x8*>(qrow + kc * 32 + g * 8);
    }

    // prologue: issue quarters Q0 (slot0) and Q1 (slot1) of tile 0
    issue_k_dma(KTb, Ks, 0, 0, w, lane);
    issue_k_dma(KTb, Ks + KQ_ELE, 0, 1, w, lane);

    float m_run = -3.0e38f;
    float s_run = 0.f;
    f32x4 accO2[16] = {};   // accO2[cb][q]: O[n = w*16 + g*4 + q][c = cb*16 + r]
    int base_t = 0;

    for (int tile = 0; tile < 18; ++tile) {
        const int m0 = tile * 128;
        f32x4 accS[8] = {};
#pragma unroll
        for (int q = 0; q < 4; ++q) {
            asm volatile("s_waitcnt vmcnt(4)\n\ts_barrier" ::: "memory");
            {   // issue quarter q+2 (2-ahead)
                int qq_i = q + 2;
                int m0_i = m0;
                if (qq_i >= 4) { qq_i -= 4; m0_i = (tile == 17) ? 0 : m0 + 128; }
                int slot_i = base_t + q + 2;
                slot_i -= (slot_i >= 3) ? 3 : 0;
                slot_i -= (slot_i >= 3) ? 3 : 0;
                issue_k_dma(KTb, Ks + slot_i * KQ_ELE, m0_i, qq_i, w, lane);
            }
            int slot = base_t + q;
            slot -= (slot >= 3) ? 3 : 0;
            slot -= (slot >= 3) ? 3 : 0;
            const __bf16* Kq = Ks + slot * KQ_ELE;
            __builtin_amdgcn_s_setprio(1);
#pragma unroll
            for (int kk = 0; kk < 2; ++kk) {
                const bf16x8 qv = qf[q * 2 + kk];
                const int swz = ((kk * 4 + g) ^ rs7) * 8;
#pragma unroll
                for (int j = 0; j < 8; ++j) {
                    const bf16x8 kf = *reinterpret_cast<const bf16x8*>(
                        Kq + (j * 16 + r) * 64 + swz);
                    accS[j] = __builtin_amdgcn_mfma_f32_16x16x32_bf16(kf, qv, accS[j], 0, 0, 0);
                }
            }
            __builtin_amdgcn_s_setprio(0);
        }
        // ---- in-lane online softmax + bf16 pack (P in registers) [proven r15]
        unsigned dwj[8][2];
        float scale;
        {
            float mj[8];
#pragma unroll
            for (int j = 0; j < 8; ++j)
                mj[j] = fmaxf(fmaxf(accS[j][0], accS[j][1]), fmaxf(accS[j][2], accS[j][3]));
            float m03 = fmaxf(fmaxf(mj[0], mj[1]), fmaxf(mj[2], mj[3]));
            float m47 = fmaxf(fmaxf(mj[4], mj[5]), fmaxf(mj[6], mj[7]));
            float tmax = fmaxf(m03, m47);
            tmax = fmaxf(tmax, __shfl_xor(tmax, 16));
            tmax = fmaxf(tmax, __shfl_xor(tmax, 32));
            const float nm = fmaxf(m_run, tmax);
            float tsj[8];
#pragma unroll
            for (int j = 0; j < 8; ++j) {
                const float pe0 = __expf(accS[j][0] - nm);
                const float pe1 = __expf(accS[j][1] - nm);
                const float pe2 = __expf(accS[j][2] - nm);
                const float pe3 = __expf(accS[j][3] - nm);
                tsj[j] = (pe0 + pe1) + (pe2 + pe3);
                dwj[j][0] = pk2(pe0, pe1);
                dwj[j][1] = pk2(pe2, pe3);
            }
            float ts = ((tsj[0] + tsj[1]) + (tsj[2] + tsj[3])) +
                       ((tsj[4] + tsj[5]) + (tsj[6] + tsj[7]));
            ts += __shfl_xor(ts, 16);
            ts += __shfl_xor(ts, 32);
            scale = __expf(m_run - nm);
            s_run = s_run * scale + ts;
            m_run = nm;
        }
        // ---- rescale accO2 (wave-local shfl) [proven r15]
        {
            float sc4[4];
#pragma unroll
            for (int q = 0; q < 4; ++q) sc4[q] = __shfl(scale, g * 4 + q);
#pragma unroll
            for (int cb = 0; cb < 16; ++cb)
#pragma unroll
                for (int q = 0; q < 4; ++q) accO2[cb][q] *= sc4[q];
        }
        // ---- redistribute P to A-operand fragments [proven r15]
        bf16x8 pa[4];
#pragma unroll
        for (int ks = 0; ks < 4; ++ks) {
            const unsigned a0 = (unsigned)__shfl((int)dwj[2 * ks][0], sb);
            const unsigned b0 = (unsigned)__shfl((int)dwj[2 * ks + 1][0], sb);
            const unsigned a1 = (unsigned)__shfl((int)dwj[2 * ks][1], sb);
            const unsigned b1 = (unsigned)__shfl((int)dwj[2 * ks + 1][1], sb);
            const unsigned a2 = (unsigned)__shfl((int)dwj[2 * ks][0], sb + 16);
            const unsigned b2 = (unsigned)__shfl((int)dwj[2 * ks + 1][0], sb + 16);
            const unsigned a3 = (unsigned)__shfl((int)dwj[2 * ks][1], sb + 16);
            const unsigned b3 = (unsigned)__shfl((int)dwj[2 * ks + 1][1], sb + 16);
            u32x4 dd;
            dd.x = ghi ? b0 : a0;
            dd.y = ghi ? b1 : a1;
            dd.z = ghi ? b2 : a2;
            dd.w = ghi ? b3 : a3;
            pa[ks] = __builtin_bit_cast(bf16x8, dd);
        }
        // ---- PV: O[n][c] += P[n][m] V[c][m]; V at-use from global [proven r15]
        __builtin_amdgcn_s_setprio(1);
#pragma unroll
        for (int cb = 0; cb < 16; ++cb) {
#pragma unroll
            for (int ks = 0; ks < 4; ++ks) {
                const bf16x8 vf = *reinterpret_cast<const bf16x8*>(
                    VBb + (size_t)(cb * 16 + r) * HW + m0 + ks * 32 + g * 8);
                accO2[cb] = __builtin_amdgcn_mfma_f32_16x16x32_bf16(pa[ks], vf, accO2[cb], 0, 0, 0);
            }
        }
        __builtin_amdgcn_s_setprio(0);
        base_t += 1;
        if (base_t == 3) base_t = 0;
    }

    // ---- epilogue [proven r15]
    const float inv = 1.f / s_run;
    float is4[4];
#pragma unroll
    for (int q = 0; q < 4; ++q) is4[q] = __shfl(inv, g * 4 + q);
    const float gm = gmp[0];
#pragma unroll
    for (int cb = 0; cb < 16; ++cb) {
        const int c = cb * 16 + r;
#pragma unroll
        for (int q = 0; q < 4; ++q) {
            const int n = n0 + w * 16 + g * 4 + q;
            const size_t idx = ((size_t)b * CH + c) * HW + n;
            const float val = gm * is4[q] * accO2[cb][q] + src[idx];
            A[idx] = val;
            AT[((size_t)b * HW + n) * 512 + aoff + c] = (__bf16)val;
        }
    }
}

// ---------------------------------------------------------------------------
// wprep: fw1 [64][512*9] fp32 -> WT bf16 [tap][m][512]
__global__ __launch_bounds__(256) void wprep(const float* __restrict__ fw1,
                                             __bf16* __restrict__ WT)
{
    const int i = blockIdx.x * 256 + threadIdx.x;   // 9*64*512 exact
    const int tap = i >> 15;
    const int rem = i & 32767;
    const int m = rem >> 9, c = rem & 511;
    WT[i] = (__bf16)fw1[(size_t)m * 4608 + c * 9 + tap];
}

// ---------------------------------------------------------------------------
// conv1 v3: K split 2-way (was 4): grid (18,2,8); 8 st-steps of 32 ch.
// Halves P4 partial traffic (151 -> 76 MB). [core proven r4-r15]
__global__ __launch_bounds__(256) void conv1_v2(
    const __bf16* __restrict__ AT, const __bf16* __restrict__ WT,
    float* __restrict__ P4)
{
    __shared__ __bf16 A9[9 * 64 * CSTR];
    __shared__ __bf16 HALO[240 * CSTR];
    const int kc = blockIdx.y, b = blockIdx.z, n0 = blockIdx.x * 128;
    const int t = threadIdx.x, lane = t & 63, wid = t >> 6;
    const int r = lane & 15, g = lane >> 4;

    int yj[2], xj[2];
#pragma unroll
    for (int j = 0; j < 2; ++j) {
        const int p = n0 + wid * 32 + j * 16 + r;
        yj[j] = p / IMG; xj[j] = p - yj[j] * IMG;
    }

    f32x4 acc[4][2] = {};

#pragma unroll 1
    for (int st = 0; st < 8; ++st) {
        const int cbase = kc * 256 + st * 32;
        if (t < 240) {
            const int nn = n0 - 56 + t;
            bf16x8 h0 = {}, h1 = {}, h2 = {}, h3 = {};
            if (nn >= 0 && nn < HW) {
                const bf16x8* sp = reinterpret_cast<const bf16x8*>(
                    AT + ((size_t)b * HW + nn) * 512 + cbase);
                h0 = sp[0]; h1 = sp[1]; h2 = sp[2]; h3 = sp[3];
            }
            bf16x8* dp = reinterpret_cast<bf16x8*>(HALO + t * CSTR);
            dp[0] = h0; dp[1] = h1; dp[2] = h2; dp[3] = h3;
        }
        {
            const int m = t >> 2, seg = t & 3;
#pragma unroll
            for (int tap = 0; tap < 9; ++tap)
                *reinterpret_cast<bf16x8*>(A9 + (tap * 64 + m) * CSTR + seg * 8) =
                    *reinterpret_cast<const bf16x8*>(WT + ((size_t)tap * 64 + m) * 512 + cbase + seg * 8);
        }
        __syncthreads();
#pragma unroll 1
        for (int tap = 0; tap < 9; ++tap) {
            const int dy = tap / 3 - 1;
            const int dx = tap - (tap / 3) * 3 - 1;
            bf16x8 bb[2];
#pragma unroll
            for (int j = 0; j < 2; ++j) {
                const bool valid = ((unsigned)(yj[j] + dy) < (unsigned)IMG) &&
                                   ((unsigned)(xj[j] + dx) < (unsigned)IMG);
                const int row = wid * 32 + j * 16 + r + 56 + dy * IMG + dx;
                bf16x8 v = {};
                if (valid) v = *reinterpret_cast<const bf16x8*>(HALO + row * CSTR + g * 8);
                bb[j] = v;
            }
            bf16x8 a[4];
#pragma unroll
            for (int i = 0; i < 4; ++i)
                a[i] = *reinterpret_cast<const bf16x8*>(A9 + (tap * 64 + i * 16 + r) * CSTR + g * 8);
#pragma unroll
            for (int i = 0; i < 4; ++i)
#pragma unroll
                for (int j = 0; j < 2; ++j)
                    acc[i][j] = __builtin_amdgcn_mfma_f32_16x16x32_bf16(a[i], bb[j], acc[i][j], 0, 0, 0);
        }
        __syncthreads();
    }
#pragma unroll
    for (int mi = 0; mi < 4; ++mi)
#pragma unroll
        for (int nj = 0; nj < 2; ++nj) {
            const int m = mi * 16 + g * 4;
            const int n = n0 + wid * 32 + nj * 16 + r;
#pragma unroll
            for (int q = 0; q < 4; ++q)
                P4[(((size_t)kc * BATCH + b) * CG + m + q) * HW + n] = acc[mi][nj][q];
        }
}

// ---------------------------------------------------------------------------
__global__ __launch_bounds__(256) void reduce_hb(
    const float* __restrict__ P4, const float* __restrict__ fb1,
    float* __restrict__ HB)
{
    const int idx = blockIdx.x * 256 + threadIdx.x;
    constexpr size_t STRIDE = (size_t)BATCH * CG * HW;
    const int m = (idx / HW) & 63;
    float s = P4[idx] + P4[idx + STRIDE];
    HB[idx] = fmaxf(s + fb1[m], 0.f);
}

// ---------------------------------------------------------------------------
__global__ __launch_bounds__(256) void gates_v2(
    const float* __restrict__ hbuf, const float* __restrict__ fw2,
    const float* __restrict__ fb2, float* __restrict__ g0buf)
{
    __shared__ float w2s[1152];
    __shared__ float par[2][4][64];
    const int t = threadIdx.x;
    for (int i = t; i < 1152; i += 256) w2s[i] = fw2[i];
    __syncthreads();
    const int px = t & 63, grp = t >> 6;
    const int idx = blockIdx.x * 64 + px;
    const int b = idx / HW;
    const int n = idx - b * HW;
    const int y = n / IMG, x = n - (n / IMG) * IMG;
    float c0 = 0.f, c1 = 0.f;
    const float* hb = hbuf + ((size_t)b * CG + grp * 16) * HW;
    for (int ci = 0; ci < 16; ++ci) {
        const float* hp = hb + (size_t)ci * HW;
        const float* w0 = &w2s[(grp * 16 + ci) * 9];
        const float* w1 = &w2s[576 + (grp * 16 + ci) * 9];
#pragma unroll
        for (int tap = 0; tap < 9; ++tap) {
            const int dy = tap / 3 - 1, dx = tap % 3 - 1;
            const int yy = y + dy, xx = x + dx;
            if (yy >= 0 && yy < IMG && xx >= 0 && xx < IMG) {
                const float hv = hp[yy * IMG + xx];
                c0 = fmaf(hv, w0[tap], c0);
                c1 = fmaf(hv, w1[tap], c1);
            }
        }
    }
    par[0][grp][px] = c0;
    par[1][grp][px] = c1;
    __syncthreads();
    if (t < 64) {
        const float s0 = par[0][0][t] + par[0][1][t] + par[0][2][t] + par[0][3][t] + fb2[0];
        const float s1 = par[1][0][t] + par[1][1][t] + par[1][2][t] + par[1][3][t] + fb2[1];
        g0buf[blockIdx.x * 64 + t] = 1.f / (1.f + __expf(s1 - s0));
    }
}

// ---------------------------------------------------------------------------
__global__ __launch_bounds__(256) void blend_kernel(
    const float* __restrict__ att1, const float* __restrict__ att2,
    const float* __restrict__ g0buf, float* __restrict__ out)
{
    const int i = blockIdx.x * 256 + threadIdx.x;
    const int r = i / 576;
    const int q = i - r * 576;
    const int b = r >> 8;
    const float4 a1 = reinterpret_cast<const float4*>(att1)[i];
    const float4 a2 = reinterpret_cast<const float4*>(att2)[i];
    const float4 g  = *reinterpret_cast<const float4*>(&g0buf[(size_t)b * HW + q * 4]);
    float4 o;
    o.x = g.x * a1.x + (1.f - g.x) * a2.x;
    o.y = g.y * a1.y + (1.f - g.y) * a2.y;
    o.z = g.z * a1.z + (1.f - g.z) * a2.z;
    o.w = g.w * a1.w + (1.f - g.w) * a2.w;
    reinterpret_cast<float4*>(out)[i] = o;
}

} // namespace

extern "C" void kernel_launch(void* const* d_in, const int* in_sizes, int n_in,
                              void* d_out, int out_size, void* d_ws, size_t ws_size,
                              hipStream_t stream)
{
    const float* x1  = (const float*)d_in[0];
    const float* x2  = (const float*)d_in[1];
    const float* wq1 = (const float*)d_in[2];
    const float* wk1 = (const float*)d_in[3];
    const float* wv1 = (const float*)d_in[4];
    const float* bv1 = (const float*)d_in[5];
    const float* g1  = (const float*)d_in[6];
    const float* wq2 = (const float*)d_in[7];
    const float* wk2 = (const float*)d_in[8];
    const float* wv2 = (const float*)d_in[9];
    const float* bv2 = (const float*)d_in[10];
    const float* g2  = (const float*)d_in[11];
    const float* fw1 = (const float*)d_in[12];
    const float* fb1 = (const float*)d_in[13];
    const float* fw2 = (const float*)d_in[14];
    const float* fb2 = (const float*)d_in[15];
    float* out = (float*)d_out;
    char*  wsb = (char*)d_ws;

    __bf16* QT1 = (__bf16*)(wsb + QT1_OFF);
    __bf16* KT1 = (__bf16*)(wsb + KT1_OFF);
    __bf16* VB1 = (__bf16*)(wsb + VB1_OFF);
    __bf16* QT2 = (__bf16*)(wsb + QT2_OFF);
    __bf16* KT2 = (__bf16*)(wsb + KT2_OFF);
    __bf16* VB2 = (__bf16*)(wsb + VB2_OFF);
    __bf16* AT  = (__bf16*)(wsb + AT_OFF);
    float*  A1  = (float*)(wsb + A1_OFF);
    float*  A2  = (float*)(wsb + A2_OFF);
    float*  HB  = (float*)(wsb + HB_OFF);
    float*  G0  = (float*)(wsb + G0_OFF);
    __bf16* WT  = (__bf16*)(wsb + WT_OFF);
    float*  P4  = (float*)(wsb + QT1_OFF);   // alias: free after attention

    (void)in_sizes; (void)n_in; (void)out_size; (void)ws_size;

    proj3_mfma<<<dim3(18, 2, 24), 256, 0, stream>>>(x1, x2, wq1, wk1, wv1, bv1, QT1, KT1, VB1);
    proj3_mfma<<<dim3(18, 2, 24), 256, 0, stream>>>(x2, x1, wq2, wk2, wv2, bv2, QT2, KT2, VB2);
    wprep<<<dim3(1152), 256, 0, stream>>>(fw1, WT);

    fused_flash<<<dim3(576), 256, 0, stream>>>(
        QT1, KT1, VB1, QT2, KT2, VB2, x1, x2, g1, g2, A1, A2, AT);

    conv1_v2<<<dim3(18, 2, 8), 256, 0, stream>>>(AT, WT, P4);
    reduce_hb<<<dim3(4608), 256, 0, stream>>>(P4, fb1, HB);
    gates_v2<<<dim3(288), 256, 0, stream>>>(HB, fw2, fb2, G0);
    blend_kernel<<<dim3(4608), 256, 0, stream>>>(A1, A2, G0, out);
}

// Round 17
// 386.838 us; speedup vs baseline: 2.6688x; 1.7429x over previous
//
#include <hip/hip_runtime.h>

namespace {

constexpr int BATCH = 8;
constexpr int CH    = 256;   // C
constexpr int HW    = 2304;  // 48*48
constexpr int IMG   = 48;
constexpr int CG    = 64;

typedef __bf16 bf16x8 __attribute__((ext_vector_type(8)));
typedef __bf16 bf16x4 __attribute__((ext_vector_type(4)));
typedef float  f32x4  __attribute__((ext_vector_type(4)));

constexpr int ROWB = 40;     // proj LDS row stride
constexpr int CSTR = 40;     // conv LDS stride
constexpr int KQ_ELE = 8192; // one K quarter: 128 rows x 64 cols bf16 (16 KB), LINEAR

// ---- ws layout (bytes) ----
constexpr size_t BF_SLAB = (size_t)BATCH * HW * CH * 2;      // 9,437,184
constexpr size_t QT1_OFF = 0;
constexpr size_t KT1_OFF = 1 * BF_SLAB;
constexpr size_t VB1_OFF = 2 * BF_SLAB;                      // bf16 [B][256][HW]
constexpr size_t QT2_OFF = 3 * BF_SLAB;
constexpr size_t KT2_OFF = 4 * BF_SLAB;
constexpr size_t VB2_OFF = 5 * BF_SLAB;
constexpr size_t AT_OFF  = 6 * BF_SLAB;                      // bf16 [B][HW][512]
constexpr size_t A1_OFF  = AT_OFF + (size_t)BATCH * HW * 512 * 2;
constexpr size_t A2_OFF  = A1_OFF + (size_t)BATCH * CH * HW * 4;
constexpr size_t HB_OFF  = A2_OFF + (size_t)BATCH * CH * HW * 4;
constexpr size_t G0_OFF  = HB_OFF + (size_t)BATCH * CG * HW * 4;
constexpr size_t WT_OFF  = G0_OFF + (size_t)BATCH * HW * 4;
// end ~= 112 MB; P4 (conv partials) aliases QT1/KT1 slabs.

// async global->LDS DMA, 16B per lane (issued where written; not sinkable)
__device__ __forceinline__ void dma16(const __bf16* g, __bf16* l) {
    __builtin_amdgcn_global_load_lds(
        (const __attribute__((address_space(1))) void*)g,
        (__attribute__((address_space(3))) void*)l,
        16, 0, 0);
}

// issue one K quarter (128 rows x 64 cols) into a linear LDS slot with
// pre-swizzled SOURCE granule (rule #21; proven r13/r14)
__device__ __forceinline__ void issue_k_dma(const __bf16* __restrict__ KTb,
                                            __bf16* Kslot, int m0_i, int qq,
                                            int w, int lane) {
    const int lrow = lane >> 3;               // 0..7
    const int lg   = (lane & 7) ^ lrow;       // swizzled source granule
    const int colb = qq * 64 + lg * 8;
#pragma unroll
    for (int qi = 0; qi < 4; ++qi) {
        const int row = (w * 4 + qi) * 8 + lrow;
        dma16(KTb + (size_t)(m0_i + row) * CH + colb,
              Kslot + (w * 4 + qi) * 512);
    }
}

// stage 16 fp32 elems/thread (convert to bf16) into [128][ROWB] LDS (256-thr)
__device__ __forceinline__ void stage_f32(const float* __restrict__ src, size_t srcStride,
                                          __bf16* dst, int t) {
    const int r = t & 127, s = t >> 7;
    const float4* sp = reinterpret_cast<const float4*>(src + (size_t)r * srcStride + s * 16);
    float4 f0 = sp[0], f1 = sp[1], f2 = sp[2], f3 = sp[3];
    bf16x8 v0, v1;
    v0[0]=(__bf16)f0.x; v0[1]=(__bf16)f0.y; v0[2]=(__bf16)f0.z; v0[3]=(__bf16)f0.w;
    v0[4]=(__bf16)f1.x; v0[5]=(__bf16)f1.y; v0[6]=(__bf16)f1.z; v0[7]=(__bf16)f1.w;
    v1[0]=(__bf16)f2.x; v1[1]=(__bf16)f2.y; v1[2]=(__bf16)f2.z; v1[3]=(__bf16)f2.w;
    v1[4]=(__bf16)f3.x; v1[5]=(__bf16)f3.y; v1[6]=(__bf16)f3.z; v1[7]=(__bf16)f3.w;
    bf16x8* dp = reinterpret_cast<bf16x8*>(dst + r * ROWB + s * 16);
    dp[0] = v0;
    dp[1] = v1;
}

// 4-wave 128x128 MFMA step (proj) [proven r3]
__device__ __forceinline__ void frag_step(const __bf16* As, const __bf16* Bs,
                                          f32x4 (&acc)[4][4], int lane, int wm, int wn) {
    const int r = lane & 15, g = lane >> 4;
    bf16x8 a[4], b[4];
#pragma unroll
    for (int i = 0; i < 4; ++i) {
        a[i] = *reinterpret_cast<const bf16x8*>(As + (wm * 64 + i * 16 + r) * ROWB + g * 8);
        b[i] = *reinterpret_cast<const bf16x8*>(Bs + (wn * 64 + i * 16 + r) * ROWB + g * 8);
    }
#pragma unroll
    for (int i = 0; i < 4; ++i)
#pragma unroll
        for (int j = 0; j < 4; ++j)
            acc[i][j] = __builtin_amdgcn_mfma_f32_16x16x32_bf16(a[i], b[j], acc[i][j], 0, 0, 0);
}

// ---------------------------------------------------------------------------
// proj3: Q/K TRANSPOSED bf16 [B][HW][256]; V natural [B][256][HW]. [proven r3-r14]
__global__ __launch_bounds__(256) void proj3_mfma(
    const float* __restrict__ Xsrc, const float* __restrict__ Xg,
    const float* __restrict__ wq, const float* __restrict__ wk,
    const float* __restrict__ wv, const float* __restrict__ bv,
    __bf16* __restrict__ QT, __bf16* __restrict__ KT, __bf16* __restrict__ VB)
{
    __shared__ __bf16 As[128 * ROWB];
    __shared__ __bf16 Bs[128 * ROWB];
    const int p = blockIdx.z >> 3;      // 0=Q 1=K 2=V
    const int b = blockIdx.z & 7;
    const float* W = (p == 0) ? wq : (p == 1) ? wk : wv;
    const float* X = (p == 0) ? Xsrc : Xg;
    const float* Xb = X + (size_t)b * CH * HW;

    const int t = threadIdx.x;
    const int lane = t & 63, wid = t >> 6;
    const int wm = wid >> 1, wn = wid & 1;
    const int m0 = blockIdx.y * 128, n0 = blockIdx.x * 128;

    f32x4 acc[4][4] = {};
    const int nB = t & 127, halfB = t >> 7;

    for (int k0 = 0; k0 < CH; k0 += 32) {
        stage_f32(W + (size_t)m0 * CH + k0, CH, As, t);
        float v[16];
#pragma unroll
        for (int kk = 0; kk < 16; ++kk)
            v[kk] = Xb[(size_t)(k0 + halfB * 16 + kk) * HW + n0 + nB];
        bf16x8 p0, p1;
#pragma unroll
        for (int kk = 0; kk < 8; ++kk) { p0[kk] = (__bf16)v[kk]; p1[kk] = (__bf16)v[kk + 8]; }
        bf16x8* dp = reinterpret_cast<bf16x8*>(Bs + nB * ROWB + halfB * 16);
        dp[0] = p0; dp[1] = p1;
        __syncthreads();
        frag_step(As, Bs, acc, lane, wm, wn);
        __syncthreads();
    }

    const int g = lane >> 4, r = lane & 15;
    if (p < 2) {
        __bf16* T = (p == 0) ? QT : KT;
#pragma unroll
        for (int mi = 0; mi < 4; ++mi)
#pragma unroll
            for (int nj = 0; nj < 4; ++nj) {
                const int mb = m0 + wm * 64 + mi * 16 + g * 4;
                const int n  = n0 + wn * 64 + nj * 16 + r;
                bf16x4 pk;
#pragma unroll
                for (int q = 0; q < 4; ++q) pk[q] = (__bf16)acc[mi][nj][q];
                *reinterpret_cast<bf16x4*>(T + ((size_t)b * HW + n) * CH + mb) = pk;
            }
    } else {
#pragma unroll
        for (int mi = 0; mi < 4; ++mi)
#pragma unroll
            for (int nj = 0; nj < 4; ++nj) {
                const int mb = m0 + wm * 64 + mi * 16 + g * 4;
                const int n  = n0 + wn * 64 + nj * 16 + r;
#pragma unroll
                for (int q = 0; q < 4; ++q)
                    VB[((size_t)b * CH + mb + q) * HW + n] = (__bf16)(acc[mi][nj][q] + bv[mb + q]);
            }
    }
}

// ---------------------------------------------------------------------------
// fused_flash v8 [proven r14: 279 us, absmax 0.02644]: DMA K-ring (3 slots,
// 2-ahead, counted vmcnt), LDS 49.4 KB -> 3 blocks/CU, P aliased into the
// dead K slot (XOR-swizzled both sides), V at-use from global.
__global__ __launch_bounds__(256, 3) void fused_flash(
    const __bf16* __restrict__ QT1, const __bf16* __restrict__ KT1, const __bf16* __restrict__ VB1,
    const __bf16* __restrict__ QT2, const __bf16* __restrict__ KT2, const __bf16* __restrict__ VB2,
    const float* __restrict__ x1, const float* __restrict__ x2,
    const float* __restrict__ g1, const float* __restrict__ g2,
    float* __restrict__ A1, float* __restrict__ A2, __bf16* __restrict__ AT)
{
    __shared__ __bf16 Ks[3 * KQ_ELE];      // 48 KB: 3 linear slots (K quarters / P)
    __shared__ float  sc_lds[64];          // 256 B

    // XCD swizzle: 576 = 8 * 72; contiguous 72-block chunk (2 z) per XCD
    const int bid  = blockIdx.x;
    const int work = (bid & 7) * 72 + (bid >> 3);
    const int z = work / 36, ntile = work - z * 36;

    const int att = z >> 3, b = z & 7;
    const __bf16* QT = att ? QT2 : QT1;
    const __bf16* KT = att ? KT2 : KT1;
    const __bf16* VB = att ? VB2 : VB1;
    const float* src = att ? x2 : x1;
    const float* gmp = att ? g2 : g1;
    float* A         = att ? A2 : A1;
    const int aoff   = att ? CH : 0;

    const int t = threadIdx.x, lane = t & 63, w = t >> 6;
    const int r = lane & 15, g = lane >> 4;
    const int rs7 = r & 7;
    const int pswz = rs7 << 4;            // P swizzle: XOR byte-bits 4..6 with row&7
    const int n0 = ntile * 64;
    const __bf16* KTb = KT + (size_t)b * HW * CH;
    const __bf16* VBb = VB + (size_t)b * CH * HW;

    // Q row in registers: q-row n0 + w*16 + r, full K=256
    bf16x8 qf[8];
    {
        const __bf16* qrow = QT + ((size_t)b * HW + n0 + w * 16 + r) * CH;
#pragma unroll
        for (int kc = 0; kc < 8; ++kc)
            qf[kc] = *reinterpret_cast<const bf16x8*>(qrow + kc * 32 + g * 8);
    }

    // prologue: issue quarters Q0 (slot0) and Q1 (slot1) of tile 0
    issue_k_dma(KTb, Ks, 0, 0, w, lane);
    issue_k_dma(KTb, Ks + KQ_ELE, 0, 1, w, lane);

    float m_run = -3.0e38f;
    float s_run = 0.f;
    f32x4 accO[4][4] = {};
    int base_t = 0;   // (tile*4) % 3 == tile % 3

    for (int tile = 0; tile < 18; ++tile) {
        const int m0 = tile * 128;
        f32x4 accS[8] = {};
#pragma unroll
        for (int q = 0; q < 4; ++q) {
            // wait: this quarter's DMA batch complete; sync all waves.
            asm volatile("s_waitcnt vmcnt(4)\n\ts_barrier" ::: "memory");
            // issue quarter q+2 (2-ahead) into slot (base_t+q+2)%3
            {
                int qq_i = q + 2;
                int m0_i = m0;
                if (qq_i >= 4) { qq_i -= 4; m0_i = (tile == 17) ? 0 : m0 + 128; }
                int slot_i = base_t + q + 2;
                slot_i -= (slot_i >= 3) ? 3 : 0;
                slot_i -= (slot_i >= 3) ? 3 : 0;
                issue_k_dma(KTb, Ks + slot_i * KQ_ELE, m0_i, qq_i, w, lane);
            }
            int slot = base_t + q;
            slot -= (slot >= 3) ? 3 : 0;
            slot -= (slot >= 3) ? 3 : 0;
            const __bf16* Kq = Ks + slot * KQ_ELE;
            __builtin_amdgcn_s_setprio(1);
#pragma unroll
            for (int kk = 0; kk < 2; ++kk) {
                const bf16x8 qv = qf[q * 2 + kk];
                const int swz = ((kk * 4 + g) ^ rs7) * 8;
#pragma unroll
                for (int j = 0; j < 8; ++j) {
                    const bf16x8 kf = *reinterpret_cast<const bf16x8*>(
                        Kq + (j * 16 + r) * 64 + swz);
                    accS[j] = __builtin_amdgcn_mfma_f32_16x16x32_bf16(kf, qv, accS[j], 0, 0, 0);
                }
            }
            __builtin_amdgcn_s_setprio(0);
        }
        // all waves done reading Q3's slot (base_t) before P overwrites it
        asm volatile("s_barrier" ::: "memory");
        char* Pb = reinterpret_cast<char*>(Ks + base_t * KQ_ELE);  // P: 64x128 bf16, swizzled
        // ---- in-lane online softmax (tree reductions) [proven r8-r13] ----
        {
            float mj[8];
#pragma unroll
            for (int j = 0; j < 8; ++j)
                mj[j] = fmaxf(fmaxf(accS[j][0], accS[j][1]), fmaxf(accS[j][2], accS[j][3]));
            float m03 = fmaxf(fmaxf(mj[0], mj[1]), fmaxf(mj[2], mj[3]));
            float m47 = fmaxf(fmaxf(mj[4], mj[5]), fmaxf(mj[6], mj[7]));
            float tmax = fmaxf(m03, m47);
            tmax = fmaxf(tmax, __shfl_xor(tmax, 16));
            tmax = fmaxf(tmax, __shfl_xor(tmax, 32));
            const float nm = fmaxf(m_run, tmax);
            float tsj[8];
#pragma unroll
            for (int j = 0; j < 8; ++j) {
                const float pe0 = __expf(accS[j][0] - nm);
                const float pe1 = __expf(accS[j][1] - nm);
                const float pe2 = __expf(accS[j][2] - nm);
                const float pe3 = __expf(accS[j][3] - nm);
                tsj[j] = (pe0 + pe1) + (pe2 + pe3);
                bf16x4 pk;
                pk[0] = (__bf16)pe0; pk[1] = (__bf16)pe1;
                pk[2] = (__bf16)pe2; pk[3] = (__bf16)pe3;
                const int off = ((w * 16 + r) * 256 + (j * 16 + g * 4) * 2) ^ pswz;
                *reinterpret_cast<bf16x4*>(Pb + off) = pk;
            }
            float ts = ((tsj[0] + tsj[1]) + (tsj[2] + tsj[3])) +
                       ((tsj[4] + tsj[5]) + (tsj[6] + tsj[7]));
            ts += __shfl_xor(ts, 16);
            ts += __shfl_xor(ts, 32);
            const float scale = __expf(m_run - nm);
            s_run = s_run * scale + ts;
            m_run = nm;
            if (lane < 16) sc_lds[w * 16 + r] = scale;
        }
        // publish P + sc: drain LDS ops only (DMAs stay in flight), sync.
        asm volatile("s_waitcnt lgkmcnt(0)\n\ts_barrier" ::: "memory");
        // ---- rescale accO by per-n scale
        {
            float scj[4];
#pragma unroll
            for (int j = 0; j < 4; ++j) scj[j] = sc_lds[j * 16 + r];
#pragma unroll
            for (int i = 0; i < 4; ++i)
#pragma unroll
                for (int j = 0; j < 4; ++j)
#pragma unroll
                    for (int q = 0; q < 4; ++q) accO[i][j][q] *= scj[j];
        }
        // ---- PV: av from global at use (VB natural), bp from swizzled P
        __builtin_amdgcn_s_setprio(1);
#pragma unroll
        for (int half = 0; half < 2; ++half) {
#pragma unroll
            for (int kk = 0; kk < 2; ++kk) {
                bf16x8 av[4], bp[4];
#pragma unroll
                for (int i = 0; i < 4; ++i)
                    av[i] = *reinterpret_cast<const bf16x8*>(
                        VBb + (size_t)(w * 64 + i * 16 + r) * HW + m0 + half * 64 + kk * 32 + g * 8);
#pragma unroll
                for (int j = 0; j < 4; ++j) {
                    const int off = ((j * 16 + r) * 256 + half * 128 + kk * 64 + g * 16) ^ pswz;
                    bp[j] = *reinterpret_cast<const bf16x8*>(Pb + off);
                }
#pragma unroll
                for (int i = 0; i < 4; ++i)
#pragma unroll
                    for (int j = 0; j < 4; ++j)
                        accO[i][j] = __builtin_amdgcn_mfma_f32_16x16x32_bf16(
                            av[i], bp[j], accO[i][j], 0, 0, 0);
            }
        }
        __builtin_amdgcn_s_setprio(0);
        // no tile-end barrier: next tile's q0 barrier precedes the DMA that
        // overwrites P's slot, guarding the WAR.
        base_t += 1;
        if (base_t == 3) base_t = 0;
    }

    // ---- epilogue: out = gamma * (1/s) * accO + src
    if (lane < 16) sc_lds[w * 16 + r] = 1.f / s_run;
    __syncthreads();
    float IS_l[4];
#pragma unroll
    for (int j = 0; j < 4; ++j) IS_l[j] = sc_lds[j * 16 + r];
    const float gm = gmp[0];
#pragma unroll
    for (int i = 0; i < 4; ++i)
#pragma unroll
        for (int j = 0; j < 4; ++j) {
            const int cb = w * 64 + i * 16 + g * 4;
            const int n  = n0 + j * 16 + r;
            const float sc = gm * IS_l[j];
            float vals[4];
#pragma unroll
            for (int q = 0; q < 4; ++q) {
                const size_t idx = ((size_t)b * CH + cb + q) * HW + n;
                vals[q] = sc * accO[i][j][q] + src[idx];
                A[idx] = vals[q];
            }
            bf16x4 pk;
#pragma unroll
            for (int q = 0; q < 4; ++q) pk[q] = (__bf16)vals[q];
            *reinterpret_cast<bf16x4*>(AT + ((size_t)b * HW + n) * 512 + aoff + cb) = pk;
        }
}

// ---------------------------------------------------------------------------
// wprep: fw1 [64][512*9] fp32 -> WT bf16 [tap][m][512]
__global__ __launch_bounds__(256) void wprep(const float* __restrict__ fw1,
                                             __bf16* __restrict__ WT)
{
    const int i = blockIdx.x * 256 + threadIdx.x;   // 9*64*512 exact
    const int tap = i >> 15;
    const int rem = i & 32767;
    const int m = rem >> 9, c = rem & 511;
    WT[i] = (__bf16)fw1[(size_t)m * 4608 + c * 9 + tap];
}

// ---------------------------------------------------------------------------
// conv1 v2 [proven r4-r14 verbatim: 4-way K split]
__global__ __launch_bounds__(256) void conv1_v2(
    const __bf16* __restrict__ AT, const __bf16* __restrict__ WT,
    float* __restrict__ P4)
{
    __shared__ __bf16 A9[9 * 64 * CSTR];
    __shared__ __bf16 HALO[240 * CSTR];
    const int kc = blockIdx.y, b = blockIdx.z, n0 = blockIdx.x * 128;
    const int t = threadIdx.x, lane = t & 63, wid = t >> 6;
    const int r = lane & 15, g = lane >> 4;

    int yj[2], xj[2];
#pragma unroll
    for (int j = 0; j < 2; ++j) {
        const int p = n0 + wid * 32 + j * 16 + r;
        yj[j] = p / IMG; xj[j] = p - yj[j] * IMG;
    }

    f32x4 acc[4][2] = {};

#pragma unroll 1
    for (int st = 0; st < 4; ++st) {
        const int cbase = kc * 128 + st * 32;
        if (t < 240) {
            const int nn = n0 - 56 + t;
            bf16x8 h0 = {}, h1 = {}, h2 = {}, h3 = {};
            if (nn >= 0 && nn < HW) {
                const bf16x8* sp = reinterpret_cast<const bf16x8*>(
                    AT + ((size_t)b * HW + nn) * 512 + cbase);
                h0 = sp[0]; h1 = sp[1]; h2 = sp[2]; h3 = sp[3];
            }
            bf16x8* dp = reinterpret_cast<bf16x8*>(HALO + t * CSTR);
            dp[0] = h0; dp[1] = h1; dp[2] = h2; dp[3] = h3;
        }
        {
            const int m = t >> 2, seg = t & 3;
#pragma unroll
            for (int tap = 0; tap < 9; ++tap)
                *reinterpret_cast<bf16x8*>(A9 + (tap * 64 + m) * CSTR + seg * 8) =
                    *reinterpret_cast<const bf16x8*>(WT + ((size_t)tap * 64 + m) * 512 + cbase + seg * 8);
        }
        __syncthreads();
#pragma unroll 1
        for (int tap = 0; tap < 9; ++tap) {
            const int dy = tap / 3 - 1;
            const int dx = tap - (tap / 3) * 3 - 1;
            bf16x8 bb[2];
#pragma unroll
            for (int j = 0; j < 2; ++j) {
                const bool valid = ((unsigned)(yj[j] + dy) < (unsigned)IMG) &&
                                   ((unsigned)(xj[j] + dx) < (unsigned)IMG);
                const int row = wid * 32 + j * 16 + r + 56 + dy * IMG + dx;
                bf16x8 v = {};
                if (valid) v = *reinterpret_cast<const bf16x8*>(HALO + row * CSTR + g * 8);
                bb[j] = v;
            }
            bf16x8 a[4];
#pragma unroll
            for (int i = 0; i < 4; ++i)
                a[i] = *reinterpret_cast<const bf16x8*>(A9 + (tap * 64 + i * 16 + r) * CSTR + g * 8);
#pragma unroll
            for (int i = 0; i < 4; ++i)
#pragma unroll
                for (int j = 0; j < 2; ++j)
                    acc[i][j] = __builtin_amdgcn_mfma_f32_16x16x32_bf16(a[i], bb[j], acc[i][j], 0, 0, 0);
        }
        __syncthreads();
    }
#pragma unroll
    for (int mi = 0; mi < 4; ++mi)
#pragma unroll
        for (int nj = 0; nj < 2; ++nj) {
            const int m = mi * 16 + g * 4;
            const int n = n0 + wid * 32 + nj * 16 + r;
#pragma unroll
            for (int q = 0; q < 4; ++q)
                P4[(((size_t)kc * BATCH + b) * CG + m + q) * HW + n] = acc[mi][nj][q];
        }
}

// ---------------------------------------------------------------------------
__global__ __launch_bounds__(256) void reduce_hb(
    const float* __restrict__ P4, const float* __restrict__ fb1,
    float* __restrict__ HB)
{
    const int idx = blockIdx.x * 256 + threadIdx.x;
    constexpr size_t STRIDE = (size_t)BATCH * CG * HW;
    const int m = (idx / HW) & 63;
    float s = P4[idx] + P4[idx + STRIDE] + P4[idx + 2 * STRIDE] + P4[idx + 3 * STRIDE];
    HB[idx] = fmaxf(s + fb1[m], 0.f);
}

// ---------------------------------------------------------------------------
__global__ __launch_bounds__(256) void gates_v2(
    const float* __restrict__ hbuf, const float* __restrict__ fw2,
    const float* __restrict__ fb2, float* __restrict__ g0buf)
{
    __shared__ float w2s[1152];
    __shared__ float par[2][4][64];
    const int t = threadIdx.x;
    for (int i = t; i < 1152; i += 256) w2s[i] = fw2[i];
    __syncthreads();
    const int px = t & 63, grp = t >> 6;
    const int idx = blockIdx.x * 64 + px;
    const int b = idx / HW;
    const int n = idx - b * HW;
    const int y = n / IMG, x = n - (n / IMG) * IMG;
    float c0 = 0.f, c1 = 0.f;
    const float* hb = hbuf + ((size_t)b * CG + grp * 16) * HW;
    for (int ci = 0; ci < 16; ++ci) {
        const float* hp = hb + (size_t)ci * HW;
        const float* w0 = &w2s[(grp * 16 + ci) * 9];
        const float* w1 = &w2s[576 + (grp * 16 + ci) * 9];
#pragma unroll
        for (int tap = 0; tap < 9; ++tap) {
            const int dy = tap / 3 - 1, dx = tap % 3 - 1;
            const int yy = y + dy, xx = x + dx;
            if (yy >= 0 && yy < IMG && xx >= 0 && xx < IMG) {
                const float hv = hp[yy * IMG + xx];
                c0 = fmaf(hv, w0[tap], c0);
                c1 = fmaf(hv, w1[tap], c1);
            }
        }
    }
    par[0][grp][px] = c0;
    par[1][grp][px] = c1;
    __syncthreads();
    if (t < 64) {
        const float s0 = par[0][0][t] + par[0][1][t] + par[0][2][t] + par[0][3][t] + fb2[0];
        const float s1 = par[1][0][t] + par[1][1][t] + par[1][2][t] + par[1][3][t] + fb2[1];
        g0buf[blockIdx.x * 64 + t] = 1.f / (1.f + __expf(s1 - s0));
    }
}

// ---------------------------------------------------------------------------
__global__ __launch_bounds__(256) void blend_kernel(
    const float* __restrict__ att1, const float* __restrict__ att2,
    const float* __restrict__ g0buf, float* __restrict__ out)
{
    const int i = blockIdx.x * 256 + threadIdx.x;
    const int r = i / 576;
    const int q = i - r * 576;
    const int b = r >> 8;
    const float4 a1 = reinterpret_cast<const float4*>(att1)[i];
    const float4 a2 = reinterpret_cast<const float4*>(att2)[i];
    const float4 g  = *reinterpret_cast<const float4*>(&g0buf[(size_t)b * HW + q * 4]);
    float4 o;
    o.x = g.x * a1.x + (1.f - g.x) * a2.x;
    o.y = g.y * a1.y + (1.f - g.y) * a2.y;
    o.z = g.z * a1.z + (1.f - g.z) * a2.z;
    o.w = g.w * a1.w + (1.f - g.w) * a2.w;
    reinterpret_cast<float4*>(out)[i] = o;
}

} // namespace

extern "C" void kernel_launch(void* const* d_in, const int* in_sizes, int n_in,
                              void* d_out, int out_size, void* d_ws, size_t ws_size,
                              hipStream_t stream)
{
    const float* x1  = (const float*)d_in[0];
    const float* x2  = (const float*)d_in[1];
    const float* wq1 = (const float*)d_in[2];
    const float* wk1 = (const float*)d_in[3];
    const float* wv1 = (const float*)d_in[4];
    const float* bv1 = (const float*)d_in[5];
    const float* g1  = (const float*)d_in[6];
    const float* wq2 = (const float*)d_in[7];
    const float* wk2 = (const float*)d_in[8];
    const float* wv2 = (const float*)d_in[9];
    const float* bv2 = (const float*)d_in[10];
    const float* g2  = (const float*)d_in[11];
    const float* fw1 = (const float*)d_in[12];
    const float* fb1 = (const float*)d_in[13];
    const float* fw2 = (const float*)d_in[14];
    const float* fb2 = (const float*)d_in[15];
    float* out = (float*)d_out;
    char*  wsb = (char*)d_ws;

    __bf16* QT1 = (__bf16*)(wsb + QT1_OFF);
    __bf16* KT1 = (__bf16*)(wsb + KT1_OFF);
    __bf16* VB1 = (__bf16*)(wsb + VB1_OFF);
    __bf16* QT2 = (__bf16*)(wsb + QT2_OFF);
    __bf16* KT2 = (__bf16*)(wsb + KT2_OFF);
    __bf16* VB2 = (__bf16*)(wsb + VB2_OFF);
    __bf16* AT  = (__bf16*)(wsb + AT_OFF);
    float*  A1  = (float*)(wsb + A1_OFF);
    float*  A2  = (float*)(wsb + A2_OFF);
    float*  HB  = (float*)(wsb + HB_OFF);
    float*  G0  = (float*)(wsb + G0_OFF);
    __bf16* WT  = (__bf16*)(wsb + WT_OFF);
    float*  P4  = (float*)(wsb + QT1_OFF);   // alias: free after attention

    (void)in_sizes; (void)n_in; (void)out_size; (void)ws_size;

    proj3_mfma<<<dim3(18, 2, 24), 256, 0, stream>>>(x1, x2, wq1, wk1, wv1, bv1, QT1, KT1, VB1);
    proj3_mfma<<<dim3(18, 2, 24), 256, 0, stream>>>(x2, x1, wq2, wk2, wv2, bv2, QT2, KT2, VB2);
    wprep<<<dim3(1152), 256, 0, stream>>>(fw1, WT);

    fused_flash<<<dim3(576), 256, 0, stream>>>(
        QT1, KT1, VB1, QT2, KT2, VB2, x1, x2, g1, g2, A1, A2, AT);

    conv1_v2<<<dim3(18, 4, 8), 256, 0, stream>>>(AT, WT, P4);
    reduce_hb<<<dim3(4608), 256, 0, stream>>>(P4, fb1, HB);
    gates_v2<<<dim3(288), 256, 0, stream>>>(HB, fw2, fb2, G0);
    blend_kernel<<<dim3(4608), 256, 0, stream>>>(A1, A2, G0, out);
}